// Round 1
// baseline (272.592 us; speedup 1.0000x reference)
//
#include <hip/hip_runtime.h>

// ---- problem constants ----
// B=2, S=1024, P=1024, D=2048, H=16, DH=128, T=P+S=2048
#define SOFT_SCALE 0.08838834764831845f   // 1/sqrt(128)
#define BSD 4194304                        // B*S*D
#define NELEM 4194304                      // elements per [B,S,D] tensor

typedef __attribute__((ext_vector_type(4))) float  f32x4;
typedef __attribute__((ext_vector_type(8))) short  bf16x8;
typedef __attribute__((ext_vector_type(4))) short  bf16x4;

__device__ __forceinline__ float bs2f(short s) {
    unsigned u = ((unsigned)(unsigned short)s) << 16;
    return __builtin_bit_cast(float, u);
}
__device__ __forceinline__ short f2bs(float f) {
    unsigned u = __builtin_bit_cast(unsigned, f);
    unsigned r = (u + 0x7fffu + ((u >> 16) & 1u)) >> 16;
    return (short)r;
}

// ---------------------------------------------------------------------------
// probe: decide whether past_k_q device buffer is int32 or int8, init scalars
// ---------------------------------------------------------------------------
__global__ void probe_init(const int* __restrict__ q, float* __restrict__ scal) {
    const int lane = threadIdx.x;
    int bad = 0;
#pragma unroll
    for (int i = 0; i < 4; ++i) {
        const int v = q[i * 64 + lane];   // first 1KB; safe for int8 buffer too
        bad |= (v < -128 || v > 127) ? 1 : 0;
    }
    const int anybad = __any(bad);
    if (lane == 0) ((int*)scal)[2] = anybad ? 0 : 1;  // 1 => int32, 0 => int8
    if (lane == 1) scal[0] = 0.f;
    if (lane == 2) scal[1] = 0.f;
}

// ---------------------------------------------------------------------------
// f32 -> bf16 elementwise (hidden_states)
// ---------------------------------------------------------------------------
__global__ void conv_bf16(const float* __restrict__ X, short* __restrict__ Y) {
    const int stride = gridDim.x * blockDim.x;
    for (int i = blockIdx.x * blockDim.x + threadIdx.x; i < NELEM / 8; i += stride) {
        const int e = i * 8;
        f32x4 a = *(const f32x4*)&X[e];
        f32x4 b = *(const f32x4*)&X[e + 4];
        bf16x8 o;
        o[0] = f2bs(a[0]); o[1] = f2bs(a[1]); o[2] = f2bs(a[2]); o[3] = f2bs(a[3]);
        o[4] = f2bs(b[0]); o[5] = f2bs(b[1]); o[6] = f2bs(b[2]); o[7] = f2bs(b[3]);
        *(bf16x8*)&Y[e] = o;
    }
}

// ---------------------------------------------------------------------------
// W[k][n] f32  ->  WT[n][k] bf16  (64x64 LDS tiles)
// ---------------------------------------------------------------------------
__global__ __launch_bounds__(256) void transpose_conv(const float* __restrict__ W,
                                                      short* __restrict__ WT) {
    __shared__ __align__(16) short Tl[64 * 68];
    const int tid = threadIdx.x;
    const int n0 = blockIdx.x * 64, k0 = blockIdx.y * 64;
#pragma unroll
    for (int i = 0; i < 4; ++i) {
        const int e = i * 1024 + tid * 4;
        const int r = e >> 6, c = e & 63;
        f32x4 f = *(const f32x4*)&W[(long)(k0 + r) * 2048 + n0 + c];
        bf16x4 s4 = { f2bs(f[0]), f2bs(f[1]), f2bs(f[2]), f2bs(f[3]) };
        *(bf16x4*)&Tl[r * 68 + c] = s4;
    }
    __syncthreads();
#pragma unroll
    for (int i = 0; i < 4; ++i) {
        const int e = i * 1024 + tid * 4;
        const int nr = e >> 6, kk = e & 63;
        bf16x4 o = { Tl[(kk + 0) * 68 + nr], Tl[(kk + 1) * 68 + nr],
                     Tl[(kk + 2) * 68 + nr], Tl[(kk + 3) * 68 + nr] };
        *(bf16x4*)&WT[(long)(n0 + nr) * 2048 + k0 + kk] = o;
    }
}

// ---------------------------------------------------------------------------
// dequantize past cache into K_full/V_full rows [b*2048 .. b*2048+1024)
// ---------------------------------------------------------------------------
__global__ void dequant_kernel(const void* __restrict__ pk, const void* __restrict__ pv,
                               const float* __restrict__ psk, const float* __restrict__ psv,
                               short* __restrict__ Kf, short* __restrict__ Vf,
                               const int* __restrict__ wsflag) {
    const int z = blockIdx.z;
    const void* src = z ? pv : pk;
    const float sc = z ? *psv : *psk;
    short* dst = z ? Vf : Kf;
    const int flag = wsflag[2];
    const int stride = gridDim.x * blockDim.x;
    for (int i = blockIdx.x * blockDim.x + threadIdx.x; i < NELEM; i += stride) {
        int v = flag ? ((const int*)src)[i] : (int)(((const signed char*)src)[i]);
        const int o = i + ((i >> 21) << 21);   // + b*2^21 : rows b*2048 + p
        dst[o] = f2bs((float)v * sc);
    }
}

// ---------------------------------------------------------------------------
// GEMM: C[m][n] = sum_k A[m][k] * Bt[n][k] + bias[n]
// A: bf16 [2048][2048], Bt: bf16 [2048][2048] (pre-transposed weight)
// tile 128(M) x 64(N), BK=32, 4 waves (2x2), 16x16x32 bf16 MFMA
// OUTMODE: 0 = f32 plain, 1 = bf16 plain, 2 = bf16 with concat row-remap
// ---------------------------------------------------------------------------
template <int OUTMODE>
__global__ __launch_bounds__(256, 2) void gemm_bf16(const short* __restrict__ A,
                                                    const short* __restrict__ Bt,
                                                    const float* __restrict__ bias,
                                                    void* __restrict__ outp) {
    __shared__ __align__(16) short Al[128 * 40];
    __shared__ __align__(16) short Bl[64 * 40];
    const int tid = threadIdx.x;
    const int m0 = blockIdx.y * 128, n0 = blockIdx.x * 64;
    const int lane = tid & 63, w = tid >> 6, l4 = lane >> 4, ln = lane & 15;
    const int wm = w >> 1, wn = w & 1;

    const int ar0 = tid >> 2, ac0 = (tid & 3) * 8;   // A rows 0..63 (+64), cols 0..24
    const int br  = tid >> 2, bc  = (tid & 3) * 8;

    const short* Abase0 = A + (long)(m0 + ar0) * 2048 + ac0;
    const short* Abase1 = A + (long)(m0 + ar0 + 64) * 2048 + ac0;
    const short* Bbase  = Bt + (long)(n0 + br) * 2048 + bc;

    f32x4 acc[4][2];
#pragma unroll
    for (int mi = 0; mi < 4; ++mi)
#pragma unroll
        for (int ni = 0; ni < 2; ++ni) acc[mi][ni] = (f32x4){0, 0, 0, 0};

    bf16x8 sa0 = *(const bf16x8*)(Abase0);
    bf16x8 sa1 = *(const bf16x8*)(Abase1);
    bf16x8 sb0 = *(const bf16x8*)(Bbase);

    for (int kt = 0; kt < 64; ++kt) {
        __syncthreads();
        *(bf16x8*)&Al[ar0 * 40 + ac0] = sa0;
        *(bf16x8*)&Al[(ar0 + 64) * 40 + ac0] = sa1;
        *(bf16x8*)&Bl[br * 40 + bc] = sb0;
        if (kt < 63) {
            const int k0 = (kt + 1) * 32;
            sa0 = *(const bf16x8*)(Abase0 + k0);
            sa1 = *(const bf16x8*)(Abase1 + k0);
            sb0 = *(const bf16x8*)(Bbase + k0);
        }
        __syncthreads();

        bf16x8 af[4], bfr[2];
#pragma unroll
        for (int mi = 0; mi < 4; ++mi)
            af[mi] = *(const bf16x8*)&Al[(wm * 64 + mi * 16 + ln) * 40 + l4 * 8];
#pragma unroll
        for (int ni = 0; ni < 2; ++ni)
            bfr[ni] = *(const bf16x8*)&Bl[(wn * 32 + ni * 16 + ln) * 40 + l4 * 8];
#pragma unroll
        for (int mi = 0; mi < 4; ++mi)
#pragma unroll
            for (int ni = 0; ni < 2; ++ni)
                acc[mi][ni] = __builtin_amdgcn_mfma_f32_16x16x32_bf16(
                    af[mi], bfr[ni], acc[mi][ni], 0, 0, 0);
    }

    // epilogue: C/D layout col=lane&15, row=(lane>>4)*4+reg
#pragma unroll
    for (int ni = 0; ni < 2; ++ni) {
        const int gn = n0 + wn * 32 + ni * 16 + ln;
        const float bv = bias[gn];
#pragma unroll
        for (int mi = 0; mi < 4; ++mi) {
#pragma unroll
            for (int r = 0; r < 4; ++r) {
                const int gm = m0 + wm * 64 + mi * 16 + l4 * 4 + r;
                const float v = acc[mi][ni][r] + bv;
                if (OUTMODE == 0) {
                    ((float*)outp)[(long)gm * 2048 + gn] = v;
                } else if (OUTMODE == 1) {
                    ((short*)outp)[(long)gm * 2048 + gn] = f2bs(v);
                } else {
                    const int gr = gm + 1024 + ((gm >> 10) << 10);  // b*2048+1024+s
                    ((short*)outp)[(long)gr * 2048 + gn] = f2bs(v);
                }
            }
        }
    }
}

// ---------------------------------------------------------------------------
// absmax over new-KV region (rows b*2048+1024 .. +1024), result in scal[z]
// ---------------------------------------------------------------------------
__global__ void absmax_kernel(const short* __restrict__ Kf, const short* __restrict__ Vf,
                              float* __restrict__ scal) {
    const int z = blockIdx.z;
    const short* src = z ? Vf : Kf;
    const int tid = threadIdx.x, lane = tid & 63, w = tid >> 6;
    float mx = 0.f;
    const int stride = gridDim.x * blockDim.x;
    for (int i = blockIdx.x * blockDim.x + tid; i < NELEM / 8; i += stride) {
        const int e = i * 8;
        const int flat = e + 2097152 + ((e >> 21) << 21);
        bf16x8 v = *(const bf16x8*)&src[flat];
#pragma unroll
        for (int j = 0; j < 8; ++j) mx = fmaxf(mx, fabsf(bs2f(v[j])));
    }
#pragma unroll
    for (int o = 32; o > 0; o >>= 1) mx = fmaxf(mx, __shfl_xor(mx, o));
    __shared__ float wred[4];
    if (lane == 0) wred[w] = mx;
    __syncthreads();
    if (tid == 0) {
        const float m2 = fmaxf(fmaxf(wred[0], wred[1]), fmaxf(wred[2], wred[3]));
        atomicMax((unsigned int*)&scal[z], __builtin_bit_cast(unsigned int, m2));
    }
}

// ---------------------------------------------------------------------------
// quantize new-KV region -> d_out (as floats), plus the two scale scalars
// out layout: [0,BSD) attn_out | [BSD,2BSD) k_q | 2BSD k_scale |
//             [2BSD+1, 3BSD+1) v_q | 3BSD+1 v_scale
// ---------------------------------------------------------------------------
__global__ void quantize_kernel(const short* __restrict__ Kf, const short* __restrict__ Vf,
                                const float* __restrict__ scal, float* __restrict__ out) {
    const int z = blockIdx.z;
    const short* src = z ? Vf : Kf;
    const float mx = scal[z];
    const float scale = mx * (1.f / 127.f);
    const float inv = (mx > 0.f) ? 127.f / mx : 0.f;
    const long ob = z ? (2L * BSD + 1) : (1L * BSD);
    if (blockIdx.x == 0 && threadIdx.x == 0)
        out[z ? (3L * BSD + 1) : (2L * BSD)] = scale;
    const int stride = gridDim.x * blockDim.x;
    for (int i = blockIdx.x * blockDim.x + threadIdx.x; i < NELEM; i += stride) {
        const int flat = i + 2097152 + ((i >> 21) << 21);
        const float x = bs2f(src[flat]);
        float q = rintf(x * inv);
        q = fminf(127.f, fmaxf(-128.f, q));
        out[ob + i] = q;
    }
}

// ---------------------------------------------------------------------------
// flash attention: 1 block = (q-tile of 64) x head x batch; 4 waves x 16 q-rows
// swapped QK^T (scores^T per lane: col=q), P kept in registers, V staged
// transposed+swizzled in LDS, O accumulated as O^T, written back via LDS.
// ---------------------------------------------------------------------------
__global__ __launch_bounds__(256, 2) void attn_kernel(const short* __restrict__ Q,
                                                      const short* __restrict__ Kf,
                                                      const short* __restrict__ Vf,
                                                      short* __restrict__ O) {
    __shared__ __align__(16) short Kl[64 * 136];
    __shared__ __align__(16) short Vt[128 * 72];
    const int qt = blockIdx.x, h = blockIdx.y, b = blockIdx.z;
    const int tid = threadIdx.x, w = tid >> 6, lane = tid & 63;
    const int l4 = lane >> 4, n = lane & 15;
    const int rg = tid >> 4, cg = tid & 15, stc = cg * 8;
    const int sIdx = qt * 64 + w * 16 + n;    // this lane's query position in S
    const int qlim = 1024 + sIdx;             // causal limit: t <= P + s

    bf16x8 qf[4];
#pragma unroll
    for (int c = 0; c < 4; ++c)
        qf[c] = *(const bf16x8*)&Q[(long)(b * 1024 + sIdx) * 2048 + h * 128 + c * 32 + l4 * 8];

    f32x4 acco[8];
#pragma unroll
    for (int i = 0; i < 8; ++i) acco[i] = (f32x4){0, 0, 0, 0};
    float m_run = -1e30f, l_run = 0.f;

    const short* Kb = Kf + (long)(b * 2048) * 2048 + h * 128;
    const short* Vb = Vf + (long)(b * 2048) * 2048 + h * 128;
    const int nt = 17 + qt;

    bf16x8 kreg[4], vreg[4];
#pragma unroll
    for (int i = 0; i < 4; ++i) kreg[i] = *(const bf16x8*)&Kb[(long)(i * 16 + rg) * 2048 + stc];
#pragma unroll
    for (int i = 0; i < 4; ++i) vreg[i] = *(const bf16x8*)&Vb[(long)(rg * 4 + i) * 2048 + stc];

    for (int t = 0; t < nt; ++t) {
        const int t0 = t * 64;
        __syncthreads();
        // stage K (row-major, padded) and V (transposed, XOR-swizzled)
#pragma unroll
        for (int i = 0; i < 4; ++i)
            *(bf16x8*)&Kl[(i * 16 + rg) * 136 + stc] = kreg[i];
#pragma unroll
        for (int j = 0; j < 8; ++j) {
            const int d = stc + j;
            bf16x4 c4 = { vreg[0][j], vreg[1][j], vreg[2][j], vreg[3][j] };
            *(bf16x4*)&Vt[d * 72 + ((rg ^ ((d >> 3) & 7)) << 2)] = c4;
        }
        if (t + 1 < nt) {
            const int t1 = (t + 1) * 64;
#pragma unroll
            for (int i = 0; i < 4; ++i)
                kreg[i] = *(const bf16x8*)&Kb[(long)(t1 + i * 16 + rg) * 2048 + stc];
#pragma unroll
            for (int i = 0; i < 4; ++i)
                vreg[i] = *(const bf16x8*)&Vb[(long)(t1 + rg * 4 + i) * 2048 + stc];
        }
        __syncthreads();

        // QK^T (scores^T): A = K rows, B = Q^T; lane holds 16 p-values for q=n
        float p[16];
#pragma unroll
        for (int kt = 0; kt < 4; ++kt) {
            f32x4 sc4 = (f32x4){0, 0, 0, 0};
#pragma unroll
            for (int c = 0; c < 4; ++c) {
                bf16x8 kfr = *(const bf16x8*)&Kl[(kt * 16 + n) * 136 + c * 32 + l4 * 8];
                sc4 = __builtin_amdgcn_mfma_f32_16x16x32_bf16(kfr, qf[c], sc4, 0, 0, 0);
            }
#pragma unroll
            for (int r = 0; r < 4; ++r) {
                const int kg = t0 + kt * 16 + l4 * 4 + r;
                const float v = sc4[r] * SOFT_SCALE;
                p[kt * 4 + r] = (kg <= qlim) ? v : -1e30f;
            }
        }
        // online softmax (reduce over the 4 lanes sharing q: xor 16, 32)
        float tmax = p[0];
#pragma unroll
        for (int i = 1; i < 16; ++i) tmax = fmaxf(tmax, p[i]);
        tmax = fmaxf(tmax, __shfl_xor(tmax, 16));
        tmax = fmaxf(tmax, __shfl_xor(tmax, 32));
        const float mnew = fmaxf(m_run, tmax);
        const float fac = __expf(m_run - mnew);
        float tsum = 0.f;
#pragma unroll
        for (int i = 0; i < 16; ++i) { p[i] = __expf(p[i] - mnew); tsum += p[i]; }
        tsum += __shfl_xor(tsum, 16);
        tsum += __shfl_xor(tsum, 32);
        l_run = l_run * fac + tsum;
        m_run = mnew;
#pragma unroll
        for (int i = 0; i < 8; ++i) acco[i] *= fac;

        // P -> bf16 B-operand fragments (k = 4*l4 + (j&3) + 16*(j>>2) + 32*k32)
        bf16x8 pb[2];
#pragma unroll
        for (int k32 = 0; k32 < 2; ++k32)
#pragma unroll
            for (int j = 0; j < 8; ++j) pb[k32][j] = f2bs(p[k32 * 8 + j]);

        // PV: O^T += V^T * P^T
#pragma unroll
        for (int dc = 0; dc < 8; ++dc) {
            const int d = dc * 16 + n;
            const int swd = ((d >> 3) & 7) << 2;
#pragma unroll
            for (int k32 = 0; k32 < 2; ++k32) {
                bf16x4 g0 = *(const bf16x4*)&Vt[d * 72 + (k32 * 32 + ((4 * l4) ^ swd))];
                bf16x4 g1 = *(const bf16x4*)&Vt[d * 72 + (k32 * 32 + ((16 + 4 * l4) ^ swd))];
                bf16x8 vf = { g0[0], g0[1], g0[2], g0[3], g1[0], g1[1], g1[2], g1[3] };
                acco[dc] = __builtin_amdgcn_mfma_f32_16x16x32_bf16(vf, pb[k32], acco[dc], 0, 0, 0);
            }
        }
    }

    // epilogue: O^T/l -> LDS -> coalesced bf16 store
    __syncthreads();
    const float inv = 1.f / l_run;
#pragma unroll
    for (int dc = 0; dc < 8; ++dc)
#pragma unroll
        for (int r = 0; r < 4; ++r)
            Kl[(w * 16 + n) * 136 + dc * 16 + l4 * 4 + r] = f2bs(acco[dc][r] * inv);
    __syncthreads();
#pragma unroll
    for (int i = 0; i < 4; ++i) {
        const int row = i * 4 + (lane >> 4);
        const int col = (lane & 15) * 8;
        bf16x8 ov = *(const bf16x8*)&Kl[(w * 16 + row) * 136 + col];
        *(bf16x8*)&O[(long)(b * 1024 + qt * 64 + w * 16 + row) * 2048 + h * 128 + col] = ov;
    }
}

// ---------------------------------------------------------------------------
extern "C" void kernel_launch(void* const* d_in, const int* in_sizes, int n_in,
                              void* d_out, int out_size, void* d_ws, size_t ws_size,
                              hipStream_t stream) {
    const float* h   = (const float*)d_in[0];
    const float* Wq  = (const float*)d_in[1];
    const float* bq  = (const float*)d_in[2];
    const float* Wk  = (const float*)d_in[3];
    const float* bk  = (const float*)d_in[4];
    const float* Wv  = (const float*)d_in[5];
    const float* bv  = (const float*)d_in[6];
    const float* Wo  = (const float*)d_in[7];
    const float* bo  = (const float*)d_in[8];
    const void*  pkq = d_in[9];
    const float* pks = (const float*)d_in[10];
    const void*  pvq = d_in[11];
    const float* pvs = (const float*)d_in[12];
    float* out = (float*)d_out;

    char* ws = (char*)d_ws;
    float* scal  = (float*)ws;                              // [0] kmax [1] vmax [2] dtype flag
    short* hbf   = (short*)(ws + 256);                      // 2048x2048 bf16 (reused as attn out)
    short* WT    = (short*)(ws + 256 + 1L * 8388608);       // 2048x2048 bf16 (transposed weight)
    short* Qbf   = (short*)(ws + 256 + 2L * 8388608);       // 2048x2048 bf16
    short* Kfull = (short*)(ws + 256 + 3L * 8388608);       // 4096x2048 bf16
    short* Vfull = (short*)(ws + 256 + 3L * 8388608 + 16777216);
    short* attnb = hbf;

    dim3 blk(256);
    dim3 gemm_grid(32, 16);     // N/64, M/128
    dim3 tr_grid(32, 32);

    probe_init<<<1, 64, 0, stream>>>((const int*)pkq, scal);
    conv_bf16<<<1024, blk, 0, stream>>>(h, hbf);
    dequant_kernel<<<dim3(512, 1, 2), blk, 0, stream>>>(pkq, pvq, pks, pvs, Kfull, Vfull,
                                                        (const int*)d_ws);
    // K = h@Wk + bk  -> Kfull rows b*2048+1024+s
    transpose_conv<<<tr_grid, blk, 0, stream>>>(Wk, WT);
    gemm_bf16<2><<<gemm_grid, blk, 0, stream>>>(hbf, WT, bk, (void*)Kfull);
    // V = h@Wv + bv
    transpose_conv<<<tr_grid, blk, 0, stream>>>(Wv, WT);
    gemm_bf16<2><<<gemm_grid, blk, 0, stream>>>(hbf, WT, bv, (void*)Vfull);
    // quantize new K/V
    absmax_kernel<<<dim3(512, 1, 2), blk, 0, stream>>>(Kfull, Vfull, scal);
    quantize_kernel<<<dim3(512, 1, 2), blk, 0, stream>>>(Kfull, Vfull, scal, out);
    // Q = h@Wq + bq
    transpose_conv<<<tr_grid, blk, 0, stream>>>(Wq, WT);
    gemm_bf16<1><<<gemm_grid, blk, 0, stream>>>(hbf, WT, bq, (void*)Qbf);
    // attention
    attn_kernel<<<dim3(16, 16, 2), blk, 0, stream>>>(Qbf, Kfull, Vfull, attnb);
    // out = attn @ Wo + bo  (f32 into d_out[0..BSD))
    transpose_conv<<<tr_grid, blk, 0, stream>>>(Wo, WT);
    gemm_bf16<0><<<gemm_grid, blk, 0, stream>>>(attnb, WT, bo, (void*)out);
}

// Round 2
// 237.479 us; speedup vs baseline: 1.1479x; 1.1479x over previous
//
#include <hip/hip_runtime.h>

// ---- problem constants ----
// B=2, S=1024, P=1024, D=2048, H=16, DH=128, T=P+S=2048
#define SOFT_SCALE 0.08838834764831845f   // 1/sqrt(128)
#define BSD 4194304                        // B*S*D
#define NELEM 4194304                      // elements per [B,S,D] tensor

typedef __attribute__((ext_vector_type(4))) float    f32x4;
typedef __attribute__((ext_vector_type(8))) short    bf16x8;
typedef __attribute__((ext_vector_type(4))) short    bf16x4;
typedef __attribute__((ext_vector_type(4))) unsigned u32x4;

__device__ __forceinline__ float bs2f(short s) {
    unsigned u = ((unsigned)(unsigned short)s) << 16;
    return __builtin_bit_cast(float, u);
}
__device__ __forceinline__ short f2bs(float f) {
    unsigned u = __builtin_bit_cast(unsigned, f);
    unsigned r = (u + 0x7fffu + ((u >> 16) & 1u)) >> 16;
    return (short)r;
}

// async global->LDS, 16B per lane (wave-uniform LDS base + lane*16)
__device__ __forceinline__ void stage16(const short* g, short* l) {
#if __has_builtin(__builtin_amdgcn_global_load_lds)
    __builtin_amdgcn_global_load_lds(
        (const __attribute__((address_space(1))) void*)g,
        (__attribute__((address_space(3))) void*)l, 16, 0, 0);
#else
    *(bf16x8*)l = *(const bf16x8*)g;
#endif
}

// ---------------------------------------------------------------------------
// probe: decide whether past_k_q device buffer is int32 or int8, init scalars
// ---------------------------------------------------------------------------
__global__ void probe_init(const int* __restrict__ q, float* __restrict__ scal) {
    const int lane = threadIdx.x;
    int bad = 0;
#pragma unroll
    for (int i = 0; i < 4; ++i) {
        const int v = q[i * 64 + lane];
        bad |= (v < -128 || v > 127) ? 1 : 0;
    }
    const int anybad = __any(bad);
    if (lane == 0) ((int*)scal)[2] = anybad ? 0 : 1;  // 1 => int32, 0 => int8
    if (lane == 1) scal[0] = 0.f;
    if (lane == 2) scal[1] = 0.f;
}

// ---------------------------------------------------------------------------
// f32 -> bf16 elementwise (hidden_states)
// ---------------------------------------------------------------------------
__global__ void conv_bf16(const float* __restrict__ X, short* __restrict__ Y) {
    const int stride = gridDim.x * blockDim.x;
    for (int i = blockIdx.x * blockDim.x + threadIdx.x; i < NELEM / 8; i += stride) {
        const int e = i * 8;
        f32x4 a = *(const f32x4*)&X[e];
        f32x4 b = *(const f32x4*)&X[e + 4];
        bf16x8 o;
        o[0] = f2bs(a[0]); o[1] = f2bs(a[1]); o[2] = f2bs(a[2]); o[3] = f2bs(a[3]);
        o[4] = f2bs(b[0]); o[5] = f2bs(b[1]); o[6] = f2bs(b[2]); o[7] = f2bs(b[3]);
        *(bf16x8*)&Y[e] = o;
    }
}

// ---------------------------------------------------------------------------
// W[k][n] f32 -> WT[n][k] bf16, up to 3 weights batched over grid.z
// ---------------------------------------------------------------------------
__global__ __launch_bounds__(256) void transpose_conv(const float* __restrict__ W0,
                                                      const float* __restrict__ W1,
                                                      const float* __restrict__ W2,
                                                      short* __restrict__ WT) {
    __shared__ __align__(16) short Tl[64 * 68];
    const float* W = blockIdx.z == 0 ? W0 : (blockIdx.z == 1 ? W1 : W2);
    short* out = WT + (long)blockIdx.z * 4194304;
    const int tid = threadIdx.x;
    const int n0 = blockIdx.x * 64, k0 = blockIdx.y * 64;
#pragma unroll
    for (int i = 0; i < 4; ++i) {
        const int e = i * 1024 + tid * 4;
        const int r = e >> 6, c = e & 63;
        f32x4 f = *(const f32x4*)&W[(long)(k0 + r) * 2048 + n0 + c];
        bf16x4 s4 = { f2bs(f[0]), f2bs(f[1]), f2bs(f[2]), f2bs(f[3]) };
        *(bf16x4*)&Tl[r * 68 + c] = s4;
    }
    __syncthreads();
#pragma unroll
    for (int i = 0; i < 4; ++i) {
        const int e = i * 1024 + tid * 4;
        const int nr = e >> 6, kk = e & 63;
        bf16x4 o = { Tl[(kk + 0) * 68 + nr], Tl[(kk + 1) * 68 + nr],
                     Tl[(kk + 2) * 68 + nr], Tl[(kk + 3) * 68 + nr] };
        *(bf16x4*)&out[(long)(n0 + nr) * 2048 + k0 + kk] = o;
    }
}

// ---------------------------------------------------------------------------
// dequantize past cache into K_full/V_full rows [b*2048 .. b*2048+1024)
// ---------------------------------------------------------------------------
__global__ void dequant_kernel(const void* __restrict__ pk, const void* __restrict__ pv,
                               const float* __restrict__ psk, const float* __restrict__ psv,
                               short* __restrict__ Kf, short* __restrict__ Vf,
                               const int* __restrict__ wsflag) {
    const int z = blockIdx.z;
    const void* src = z ? pv : pk;
    const float sc = z ? *psv : *psk;
    short* dst = z ? Vf : Kf;
    const int flag = wsflag[2];
    const int stride = gridDim.x * blockDim.x;
    for (int i = blockIdx.x * blockDim.x + threadIdx.x; i < NELEM / 8; i += stride) {
        const int e = i * 8;
        int vals[8];
        if (flag) {
            const int* s = (const int*)src + e;
            *(int4*)&vals[0] = *(const int4*)&s[0];
            *(int4*)&vals[4] = *(const int4*)&s[4];
        } else {
            const int2 wv = *(const int2*)((const char*)src + e);
#pragma unroll
            for (int j = 0; j < 4; ++j) vals[j] = (int)(signed char)(wv.x >> (8 * j));
#pragma unroll
            for (int j = 0; j < 4; ++j) vals[4 + j] = (int)(signed char)(wv.y >> (8 * j));
        }
        bf16x8 o;
#pragma unroll
        for (int j = 0; j < 8; ++j) o[j] = f2bs((float)vals[j] * sc);
        *(bf16x8*)&dst[e + ((e >> 21) << 21)] = o;
    }
}

// ---------------------------------------------------------------------------
// GEMM (m97-style): C[m][n] = sum_k A[m][k]*Bt[n][k] + bias[n]  (then *scale)
// 128x128 tile, BK=32, 4 waves (2x2), double-buffered LDS, global_load_lds,
// 2-phase pipeline. grid.z==3 => batched QKV (z0:Q mode1*scale, z1/z2 mode2).
// mode: 0 = f32 plain, 1 = bf16 plain, 2 = bf16 concat row-remap
// ---------------------------------------------------------------------------
__global__ __launch_bounds__(256, 2) void gemm_m97(
    const short* __restrict__ A,
    const short* __restrict__ Bt0, const short* __restrict__ Bt1, const short* __restrict__ Bt2,
    const float* __restrict__ bi0, const float* __restrict__ bi1, const float* __restrict__ bi2,
    void* __restrict__ o0, void* __restrict__ o1, void* __restrict__ o2,
    int mode_sgl, float scale_sgl) {
    __shared__ __align__(16) short Al[2][4096];
    __shared__ __align__(16) short Bl[2][4096];
    const int nbx = gridDim.x, nby = gridDim.y, nbz = gridDim.z;
    const int nwg = nbx * nby * nbz;
    const int orig = blockIdx.x + nbx * (blockIdx.y + nby * blockIdx.z);
    const int cpx = nwg >> 3;
    int swz = (orig & 7) * cpx + (orig >> 3);      // XCD swizzle (nwg % 8 == 0)
    const int bx = swz % nbx; swz /= nbx;
    const int by = swz % nby;
    const int bz = swz / nby;

    const short* Bt   = bz == 0 ? Bt0 : (bz == 1 ? Bt1 : Bt2);
    const float* bias = bz == 0 ? bi0 : (bz == 1 ? bi1 : bi2);
    void* outp        = bz == 0 ? o0  : (bz == 1 ? o1  : o2);
    int mode; float scl;
    if (nbz == 3) { mode = (bz == 0) ? 1 : 2; scl = (bz == 0) ? SOFT_SCALE : 1.f; }
    else          { mode = mode_sgl;          scl = scale_sgl; }

    const int tid = threadIdx.x, lane = tid & 63, w = tid >> 6;
    const int wm = w >> 1, wn = w & 1, l4 = lane >> 4, ln = lane & 15;
    const int m0 = by * 128, n0 = bx * 128;

    const short* gA0 = A  + (long)(m0 + (tid >> 2)) * 2048 + (tid & 3) * 8;
    const short* gA1 = gA0 + 64 * 2048;
    const short* gB0 = Bt + (long)(n0 + (tid >> 2)) * 2048 + (tid & 3) * 8;
    const short* gB1 = gB0 + 64 * 2048;

    f32x4 acc[4][4];
#pragma unroll
    for (int mi = 0; mi < 4; ++mi)
#pragma unroll
        for (int ni = 0; ni < 4; ++ni) acc[mi][ni] = (f32x4){0, 0, 0, 0};

#define STAGE_G(buf, ko)                                   \
    do {                                                   \
        stage16(gA0 + (ko), &Al[buf][tid * 8]);            \
        stage16(gA1 + (ko), &Al[buf][2048 + tid * 8]);     \
        stage16(gB0 + (ko), &Bl[buf][tid * 8]);            \
        stage16(gB1 + (ko), &Bl[buf][2048 + tid * 8]);     \
    } while (0)

    STAGE_G(0, 0);
    asm volatile("s_waitcnt vmcnt(0)" ::: "memory");
    __syncthreads();
    int cur = 0;
    for (int kt = 0; kt < 64; ++kt) {
        if (kt < 63) STAGE_G(cur ^ 1, (kt + 1) * 32);
        bf16x8 af[4], bfr[4];
#pragma unroll
        for (int mi = 0; mi < 4; ++mi)
            af[mi] = *(const bf16x8*)&Al[cur][(wm * 64 + mi * 16 + ln) * 32 + l4 * 8];
#pragma unroll
        for (int ni = 0; ni < 4; ++ni)
            bfr[ni] = *(const bf16x8*)&Bl[cur][(wn * 64 + ni * 16 + ln) * 32 + l4 * 8];
#pragma unroll
        for (int mi = 0; mi < 4; ++mi)
#pragma unroll
            for (int ni = 0; ni < 4; ++ni)
                acc[mi][ni] = __builtin_amdgcn_mfma_f32_16x16x32_bf16(
                    af[mi], bfr[ni], acc[mi][ni], 0, 0, 0);
        asm volatile("s_waitcnt vmcnt(0)" ::: "memory");
        __syncthreads();
        cur ^= 1;
    }
#undef STAGE_G

#pragma unroll
    for (int ni = 0; ni < 4; ++ni) {
        const int gn = n0 + wn * 64 + ni * 16 + ln;
        const float bv = bias[gn];
#pragma unroll
        for (int mi = 0; mi < 4; ++mi) {
#pragma unroll
            for (int r = 0; r < 4; ++r) {
                const int gm = m0 + wm * 64 + mi * 16 + l4 * 4 + r;
                const float v = (acc[mi][ni][r] + bv) * scl;
                if (mode == 0) {
                    ((float*)outp)[(long)gm * 2048 + gn] = v;
                } else if (mode == 1) {
                    ((short*)outp)[(long)gm * 2048 + gn] = f2bs(v);
                } else {
                    const int gr = gm + 1024 + ((gm >> 10) << 10);  // b*2048+1024+s
                    ((short*)outp)[(long)gr * 2048 + gn] = f2bs(v);
                }
            }
        }
    }
}

// ---------------------------------------------------------------------------
// absmax over new-KV region (rows b*2048+1024 .. +1024), result in scal[z]
// ---------------------------------------------------------------------------
__global__ void absmax_kernel(const short* __restrict__ Kf, const short* __restrict__ Vf,
                              float* __restrict__ scal) {
    const int z = blockIdx.z;
    const short* src = z ? Vf : Kf;
    const int tid = threadIdx.x, lane = tid & 63, w = tid >> 6;
    float mx = 0.f;
    const int stride = gridDim.x * blockDim.x;
    for (int i = blockIdx.x * blockDim.x + tid; i < NELEM / 8; i += stride) {
        const int e = i * 8;
        const int flat = e + 2097152 + ((e >> 21) << 21);
        bf16x8 v = *(const bf16x8*)&src[flat];
#pragma unroll
        for (int j = 0; j < 8; ++j) mx = fmaxf(mx, fabsf(bs2f(v[j])));
    }
#pragma unroll
    for (int o = 32; o > 0; o >>= 1) mx = fmaxf(mx, __shfl_xor(mx, o));
    __shared__ float wred[4];
    if (lane == 0) wred[w] = mx;
    __syncthreads();
    if (tid == 0) {
        const float m2 = fmaxf(fmaxf(wred[0], wred[1]), fmaxf(wred[2], wred[3]));
        atomicMax((unsigned int*)&scal[z], __builtin_bit_cast(unsigned int, m2));
    }
}

// ---------------------------------------------------------------------------
// quantize new-KV region -> d_out (as floats), plus the two scale scalars
// ---------------------------------------------------------------------------
__global__ void quantize_kernel(const short* __restrict__ Kf, const short* __restrict__ Vf,
                                const float* __restrict__ scal, float* __restrict__ out) {
    const int z = blockIdx.z;
    const short* src = z ? Vf : Kf;
    const float mx = scal[z];
    const float scale = mx * (1.f / 127.f);
    const float inv = (mx > 0.f) ? 127.f / mx : 0.f;
    const long ob = z ? (2L * BSD + 1) : (1L * BSD);
    if (blockIdx.x == 0 && threadIdx.x == 0)
        out[z ? (3L * BSD + 1) : (2L * BSD)] = scale;
    const int stride = gridDim.x * blockDim.x;
    for (int i = blockIdx.x * blockDim.x + threadIdx.x; i < NELEM; i += stride) {
        const int flat = i + 2097152 + ((i >> 21) << 21);
        const float x = bs2f(src[flat]);
        float q = rintf(x * inv);
        q = fminf(127.f, fmaxf(-128.f, q));
        out[ob + i] = q;
    }
}

// ---------------------------------------------------------------------------
// flash attention: Q pre-scaled by 1/sqrt(DH). qt remapped via z so the two
// co-resident blocks (z=0/1, same x,y) have complementary work (sum const).
// ---------------------------------------------------------------------------
__global__ __launch_bounds__(256, 2) void attn_kernel(const short* __restrict__ Q,
                                                      const short* __restrict__ Kf,
                                                      const short* __restrict__ Vf,
                                                      short* __restrict__ O) {
    __shared__ __align__(16) short Kl[64 * 136];
    __shared__ __align__(16) short Vt[128 * 72];
    const int b = blockIdx.z, h = blockIdx.y;
    const int qt = (b == 0) ? blockIdx.x : (15 - blockIdx.x);   // balance pairing
    const int tid = threadIdx.x, w = tid >> 6, lane = tid & 63;
    const int l4 = lane >> 4, n = lane & 15;
    const int rg = tid >> 4, cg = tid & 15, stc = cg * 8;
    const int sIdx = qt * 64 + w * 16 + n;
    const int qlim = 1024 + sIdx;

    bf16x8 qf[4];
#pragma unroll
    for (int c = 0; c < 4; ++c)
        qf[c] = *(const bf16x8*)&Q[(long)(b * 1024 + sIdx) * 2048 + h * 128 + c * 32 + l4 * 8];

    f32x4 acco[8];
#pragma unroll
    for (int i = 0; i < 8; ++i) acco[i] = (f32x4){0, 0, 0, 0};
    float m_run = -1e30f, l_run = 0.f;

    const short* Kb = Kf + (long)(b * 2048) * 2048 + h * 128;
    const short* Vb = Vf + (long)(b * 2048) * 2048 + h * 128;
    const int nt = 17 + qt;

    bf16x8 kreg[4], vreg[4];
#pragma unroll
    for (int i = 0; i < 4; ++i) kreg[i] = *(const bf16x8*)&Kb[(long)(i * 16 + rg) * 2048 + stc];
#pragma unroll
    for (int i = 0; i < 4; ++i) vreg[i] = *(const bf16x8*)&Vb[(long)(rg * 4 + i) * 2048 + stc];

    for (int t = 0; t < nt; ++t) {
        const int t0 = t * 64;
        __syncthreads();
#pragma unroll
        for (int i = 0; i < 4; ++i)
            *(bf16x8*)&Kl[(i * 16 + rg) * 136 + stc] = kreg[i];
#pragma unroll
        for (int j = 0; j < 8; ++j) {
            const int d = stc + j;
            bf16x4 c4 = { vreg[0][j], vreg[1][j], vreg[2][j], vreg[3][j] };
            *(bf16x4*)&Vt[d * 72 + ((rg ^ ((d >> 3) & 7)) << 2)] = c4;
        }
        if (t + 1 < nt) {
            const int t1 = (t + 1) * 64;
#pragma unroll
            for (int i = 0; i < 4; ++i)
                kreg[i] = *(const bf16x8*)&Kb[(long)(t1 + i * 16 + rg) * 2048 + stc];
#pragma unroll
            for (int i = 0; i < 4; ++i)
                vreg[i] = *(const bf16x8*)&Vb[(long)(t1 + rg * 4 + i) * 2048 + stc];
        }
        __syncthreads();

        // QK^T (scores^T): lane holds 16 p-values for q-row sIdx
        float p[16];
        __builtin_amdgcn_s_setprio(1);
#pragma unroll
        for (int kt = 0; kt < 4; ++kt) {
            f32x4 sc4 = (f32x4){0, 0, 0, 0};
#pragma unroll
            for (int c = 0; c < 4; ++c) {
                bf16x8 kfr = *(const bf16x8*)&Kl[(kt * 16 + n) * 136 + c * 32 + l4 * 8];
                sc4 = __builtin_amdgcn_mfma_f32_16x16x32_bf16(kfr, qf[c], sc4, 0, 0, 0);
            }
#pragma unroll
            for (int r = 0; r < 4; ++r) {
                const int kg = t0 + kt * 16 + l4 * 4 + r;
                p[kt * 4 + r] = (kg <= qlim) ? sc4[r] : -1e30f;
            }
        }
        __builtin_amdgcn_s_setprio(0);

        float tmax = p[0];
#pragma unroll
        for (int i = 1; i < 16; ++i) tmax = fmaxf(tmax, p[i]);
        tmax = fmaxf(tmax, __shfl_xor(tmax, 16));
        tmax = fmaxf(tmax, __shfl_xor(tmax, 32));
        const float mnew = fmaxf(m_run, tmax);
        const float fac = __expf(m_run - mnew);
        float tsum = 0.f;
#pragma unroll
        for (int i = 0; i < 16; ++i) { p[i] = __expf(p[i] - mnew); tsum += p[i]; }
        tsum += __shfl_xor(tsum, 16);
        tsum += __shfl_xor(tsum, 32);
        l_run = l_run * fac + tsum;
        m_run = mnew;
#pragma unroll
        for (int i = 0; i < 8; ++i) acco[i] *= fac;

        // P -> bf16 via v_cvt_pk_bf16_f32 (RNE), same element order as before
        u32x4 pw0, pw1;
#pragma unroll
        for (int wd = 0; wd < 4; ++wd) {
            unsigned r0, r1;
            asm("v_cvt_pk_bf16_f32 %0, %1, %2" : "=v"(r0) : "v"(p[2 * wd]), "v"(p[2 * wd + 1]));
            asm("v_cvt_pk_bf16_f32 %0, %1, %2" : "=v"(r1) : "v"(p[8 + 2 * wd]), "v"(p[8 + 2 * wd + 1]));
            pw0[wd] = r0; pw1[wd] = r1;
        }
        bf16x8 pb[2] = { __builtin_bit_cast(bf16x8, pw0), __builtin_bit_cast(bf16x8, pw1) };

        __builtin_amdgcn_s_setprio(1);
#pragma unroll
        for (int dc = 0; dc < 8; ++dc) {
            const int d = dc * 16 + n;
            const int swd = ((d >> 3) & 7) << 2;
#pragma unroll
            for (int k32 = 0; k32 < 2; ++k32) {
                bf16x4 g0 = *(const bf16x4*)&Vt[d * 72 + (k32 * 32 + ((4 * l4) ^ swd))];
                bf16x4 g1 = *(const bf16x4*)&Vt[d * 72 + (k32 * 32 + ((16 + 4 * l4) ^ swd))];
                bf16x8 vf = { g0[0], g0[1], g0[2], g0[3], g1[0], g1[1], g1[2], g1[3] };
                acco[dc] = __builtin_amdgcn_mfma_f32_16x16x32_bf16(vf, pb[k32], acco[dc], 0, 0, 0);
            }
        }
        __builtin_amdgcn_s_setprio(0);
    }

    __syncthreads();
    const float inv = 1.f / l_run;
#pragma unroll
    for (int dc = 0; dc < 8; ++dc)
#pragma unroll
        for (int r = 0; r < 4; ++r)
            Kl[(w * 16 + n) * 136 + dc * 16 + l4 * 4 + r] = f2bs(acco[dc][r] * inv);
    __syncthreads();
#pragma unroll
    for (int i = 0; i < 4; ++i) {
        const int row = i * 4 + (lane >> 4);
        const int col = (lane & 15) * 8;
        bf16x8 ov = *(const bf16x8*)&Kl[(w * 16 + row) * 136 + col];
        *(bf16x8*)&O[(long)(b * 1024 + qt * 64 + w * 16 + row) * 2048 + h * 128 + col] = ov;
    }
}

// ---------------------------------------------------------------------------
extern "C" void kernel_launch(void* const* d_in, const int* in_sizes, int n_in,
                              void* d_out, int out_size, void* d_ws, size_t ws_size,
                              hipStream_t stream) {
    const float* h   = (const float*)d_in[0];
    const float* Wq  = (const float*)d_in[1];
    const float* bq  = (const float*)d_in[2];
    const float* Wk  = (const float*)d_in[3];
    const float* bk  = (const float*)d_in[4];
    const float* Wv  = (const float*)d_in[5];
    const float* bv  = (const float*)d_in[6];
    const float* Wo  = (const float*)d_in[7];
    const float* bo  = (const float*)d_in[8];
    const void*  pkq = d_in[9];
    const float* pks = (const float*)d_in[10];
    const void*  pvq = d_in[11];
    const float* pvs = (const float*)d_in[12];
    float* out = (float*)d_out;

    char* ws = (char*)d_ws;
    dim3 blk(256);
    dim3 tr_grid(32, 32);
    const bool big = (ws_size >= 75500000ull);

    if (big) {
        float* scal  = (float*)ws;
        short* hbf   = (short*)(ws + 256);                       // 8.4MB (reused as attn out)
        short* WT3   = (short*)(ws + 256 + 1L * 8388608);        // 25.2MB (3 transposed weights)
        short* Qbf   = (short*)(ws + 256 + 4L * 8388608);        // 8.4MB
        short* Kfull = (short*)(ws + 256 + 5L * 8388608);        // 16.8MB
        short* Vfull = (short*)(ws + 256 + 5L * 8388608 + 16777216);
        short* attnb = hbf;

        probe_init<<<1, 64, 0, stream>>>((const int*)pkq, scal);
        conv_bf16<<<1024, blk, 0, stream>>>(h, hbf);
        dequant_kernel<<<dim3(256, 1, 2), blk, 0, stream>>>(pkq, pvq, pks, pvs, Kfull, Vfull,
                                                            (const int*)d_ws);
        transpose_conv<<<dim3(32, 32, 3), blk, 0, stream>>>(Wq, Wk, Wv, WT3);
        gemm_m97<<<dim3(16, 16, 3), blk, 0, stream>>>(hbf, WT3, WT3 + 4194304, WT3 + 8388608,
                                                      bq, bk, bv, Qbf, Kfull, Vfull, 0, 1.f);
        absmax_kernel<<<dim3(512, 1, 2), blk, 0, stream>>>(Kfull, Vfull, scal);
        quantize_kernel<<<dim3(512, 1, 2), blk, 0, stream>>>(Kfull, Vfull, scal, out);
        attn_kernel<<<dim3(16, 16, 2), blk, 0, stream>>>(Qbf, Kfull, Vfull, attnb);
        transpose_conv<<<dim3(32, 32, 1), blk, 0, stream>>>(Wo, Wo, Wo, WT3);
        gemm_m97<<<dim3(16, 16, 1), blk, 0, stream>>>(attnb, WT3, WT3, WT3, bo, bo, bo,
                                                      out, out, out, 0, 1.f);
    } else {
        float* scal  = (float*)ws;
        short* hbf   = (short*)(ws + 256);
        short* WT    = (short*)(ws + 256 + 1L * 8388608);
        short* Qbf   = (short*)(ws + 256 + 2L * 8388608);
        short* Kfull = (short*)(ws + 256 + 3L * 8388608);
        short* Vfull = (short*)(ws + 256 + 3L * 8388608 + 16777216);
        short* attnb = hbf;

        probe_init<<<1, 64, 0, stream>>>((const int*)pkq, scal);
        conv_bf16<<<1024, blk, 0, stream>>>(h, hbf);
        dequant_kernel<<<dim3(256, 1, 2), blk, 0, stream>>>(pkq, pvq, pks, pvs, Kfull, Vfull,
                                                            (const int*)d_ws);
        transpose_conv<<<dim3(32, 32, 1), blk, 0, stream>>>(Wk, Wk, Wk, WT);
        gemm_m97<<<dim3(16, 16, 1), blk, 0, stream>>>(hbf, WT, WT, WT, bk, bk, bk,
                                                      Kfull, Kfull, Kfull, 2, 1.f);
        transpose_conv<<<dim3(32, 32, 1), blk, 0, stream>>>(Wv, Wv, Wv, WT);
        gemm_m97<<<dim3(16, 16, 1), blk, 0, stream>>>(hbf, WT, WT, WT, bv, bv, bv,
                                                      Vfull, Vfull, Vfull, 2, 1.f);
        absmax_kernel<<<dim3(512, 1, 2), blk, 0, stream>>>(Kfull, Vfull, scal);
        quantize_kernel<<<dim3(512, 1, 2), blk, 0, stream>>>(Kfull, Vfull, scal, out);
        transpose_conv<<<dim3(32, 32, 1), blk, 0, stream>>>(Wq, Wq, Wq, WT);
        gemm_m97<<<dim3(16, 16, 1), blk, 0, stream>>>(hbf, WT, WT, WT, bq, bq, bq,
                                                      Qbf, Qbf, Qbf, 1, SOFT_SCALE);
        attn_kernel<<<dim3(16, 16, 2), blk, 0, stream>>>(Qbf, Kfull, Vfull, attnb);
        transpose_conv<<<dim3(32, 32, 1), blk, 0, stream>>>(Wo, Wo, Wo, WT);
        gemm_m97<<<dim3(16, 16, 1), blk, 0, stream>>>(attnb, WT, WT, WT, bo, bo, bo,
                                                      out, out, out, 0, 1.f);
    }
}